// Round 6
// baseline (3657.145 us; speedup 1.0000x reference)
//
#include <hip/hip_runtime.h>
#include <hip/hip_fp16.h>

#define LOG2PI_F 1.8378770664093453f

typedef _Float16 hf8_t __attribute__((ext_vector_type(8)));
typedef float f32x4_t __attribute__((ext_vector_type(4)));

__device__ __forceinline__ unsigned int packh2(float lo, float hi) {
  unsigned int l = (unsigned int)__half_as_ushort(__float2half(lo));
  unsigned int h = (unsigned int)__half_as_ushort(__float2half(hi));
  return (h << 16) | l;
}

__device__ __forceinline__ float sigmoid_f(float x) { return 1.f / (1.f + __expf(-x)); }
__device__ __forceinline__ float silu_f(float x) { return x * sigmoid_f(x); }
__device__ __forceinline__ float softplus_f(float x) {
  return fmaxf(x, 0.f) + log1pf(__expf(-fabsf(x)));
}
__device__ __forceinline__ float tanh_f(float x) {
  float ax = fabsf(x);
  float e = __expf(2.f * ax);
  return copysignf(1.f - 2.f / (e + 1.f), x);
}

// ---------------- prep kernels ----------------
__global__ void transpose_k(const float* __restrict__ in, float* __restrict__ out,
                            int R, int C) {
  int i = blockIdx.x * 256 + threadIdx.x;
  if (i < R * C) {
    int r = i / C, c = i % C;
    out[c * R + r] = in[i];
  }
}

// W_hh [768,256] fp32 -> MFMA A-fragment layout, f16 pairs packed in dwords.
// uint4 index u4 = (mt*8 + kt)*64 + lane  (mt = 0..47 M-tile over gate rows,
// kt = 0..7 K-tile). Lane l holds A[row = l&15][k = 8*(l>>4) + j], j=0..7.
// dword d of the uint4 = pairs (2d, 2d+1) of that 8-element k-slice.
__global__ void whh_mfma_pack(const float* __restrict__ W, unsigned int* __restrict__ Wmf) {
  int idx = blockIdx.x * 256 + threadIdx.x;  // dword index
  if (idx < 98304) {
    int d = idx & 3;
    int u4 = idx >> 2;
    int lane = u4 & 63;
    int rem = u4 >> 6;   // mt*8 + kt
    int kt = rem & 7;
    int mt = rem >> 3;
    int row = 16 * mt + (lane & 15);
    int col = 32 * kt + 8 * (lane >> 4) + 2 * d;
    Wmf[idx] = packh2(W[row * 256 + col], W[row * 256 + col + 1]);
  }
}

// ---------------- gi = x @ W_ih^T + b_ih (+ b_hh folded for r,z), M-tile 8 -------
__global__ void gi_gemm(const float* __restrict__ x, const float* __restrict__ WT,
                        const float* __restrict__ bih, const float* __restrict__ bhh,
                        float* __restrict__ gi) {
  int m0 = blockIdx.x * 8;
  int g = threadIdx.x;
  __shared__ float xs[8][64];
  for (int i = g; i < 512; i += 256) xs[i >> 6][i & 63] = x[m0 * 64 + i];
  __syncthreads();
  float b0 = bih[g] + bhh[g];              // r: fold b_hh
  float b1 = bih[g + 256] + bhh[g + 256];  // z: fold b_hh
  float b2 = bih[g + 512];                 // n: b_hh applied inside tanh arg
  float a0[8], a1[8], a2[8];
#pragma unroll
  for (int r = 0; r < 8; r++) { a0[r] = b0; a1[r] = b1; a2[r] = b2; }
  for (int k = 0; k < 64; k++) {
    const float* w = WT + k * 768;
    float w0 = w[g], w1 = w[g + 256], w2 = w[g + 512];
#pragma unroll
    for (int r = 0; r < 8; r++) {
      float xv = xs[r][k];
      a0[r] = fmaf(w0, xv, a0[r]);
      a1[r] = fmaf(w1, xv, a1[r]);
      a2[r] = fmaf(w2, xv, a2[r]);
    }
  }
#pragma unroll
  for (int r = 0; r < 8; r++) {
    float* o = gi + (m0 + r) * 768;
    o[g] = a0[r];
    o[g + 256] = a1[r];
    o[g + 512] = a2[r];
  }
}

// ---------------- GRU scan via MFMA: one block/batch, 768 threads = 12 waves -----
// Wave w owns gate rows [64w, 64w+64) = 4 M-tiles; weights = 32 A-fragments
// (128 dwords) living in AGPRs, read natively by the matrix pipe (no
// v_accvgpr_read tax, the bottleneck of R0-R5). B operand = h broadcast into all
// 16 columns (every column computes the same matvec; no masking needed).
__global__ __launch_bounds__(768, 3) void gru_kernel(
    const uint4* __restrict__ Wmf,   // [12*4*8*64] uint4 A-fragments
    const float* __restrict__ gi,    // [8,2048,768], b_hh r/z pre-folded
    const float* __restrict__ bhh,   // [768] (n bias used)
    float* __restrict__ h_seq)       // [8,2048,256]
{
  const int b = blockIdx.x;
  const int tid = threadIdx.x;
  const int w = tid >> 6;
  const int lane = tid & 63;

  uint4 wA[32];
#pragma unroll
  for (int i = 0; i < 32; i++) wA[i] = Wmf[(w * 32 + i) * 64 + lane];

  __shared__ __align__(16) unsigned int hpk[2][128];  // h as f16[256], double-buffered
  __shared__ __align__(16) float als[768];            // raw hh-dots
  if (tid < 128) hpk[0][tid] = 0u;

  const float* gib = gi + b * 2048 * 768;
  float* hsb = h_seq + b * 2048 * 256;

  float h = 0.f, bn = 0.f, gr = 0.f, gz = 0.f, gn = 0.f;
  if (tid < 256) {
    bn = bhh[512 + tid];
    gr = gib[tid];
    gz = gib[256 + tid];
    gn = gib[512 + tid];
  }
  __syncthreads();

  for (int t = 0; t < 2048; t++) {
    float grn = 0.f, gzn = 0.f, gnn = 0.f;
    if (tid < 256) {  // prefetch next step's gi (hidden under MFMA phase)
      const float* gnx = gib + min(t + 1, 2047) * 768;
      grn = gnx[tid];
      gzn = gnx[256 + tid];
      gnn = gnx[512 + tid];
    }

    // B-fragment source: lane l reads h-pairs [16kt + 4*(l>>4) .. +3] (broadcast
    // within each 16-lane group; 16 consecutive dwords -> conflict-free).
    const char* hb = (const char*)(hpk[t & 1]) + 16 * (lane >> 4);
    f32x4_t a0 = {0.f, 0.f, 0.f, 0.f}, a1 = a0, a2 = a0, a3 = a0;
    uint4 hc = *(const uint4*)(hb);
    uint4 hn = *(const uint4*)(hb + 64);
#pragma unroll
    for (int kt = 0; kt < 8; kt++) {
      hf8_t bf = __builtin_bit_cast(hf8_t, hc);
      a0 = __builtin_amdgcn_mfma_f32_16x16x32_f16(
          __builtin_bit_cast(hf8_t, wA[kt]), bf, a0, 0, 0, 0);
      a1 = __builtin_amdgcn_mfma_f32_16x16x32_f16(
          __builtin_bit_cast(hf8_t, wA[8 + kt]), bf, a1, 0, 0, 0);
      a2 = __builtin_amdgcn_mfma_f32_16x16x32_f16(
          __builtin_bit_cast(hf8_t, wA[16 + kt]), bf, a2, 0, 0, 0);
      a3 = __builtin_amdgcn_mfma_f32_16x16x32_f16(
          __builtin_bit_cast(hf8_t, wA[24 + kt]), bf, a3, 0, 0, 0);
      hc = hn;
      if (kt < 6) hn = *(const uint4*)(hb + 64 * (kt + 2));
    }
    // D: col=lane&15 (all cols identical), row=4*(lane>>4)+reg.
    // Lanes with (lane&15)==0 write rows [64w+16m+4q .. +3] as float4.
    if ((lane & 15) == 0) {
      int rbase = 64 * w + 4 * (lane >> 4);
      *(f32x4_t*)&als[rbase] = a0;
      *(f32x4_t*)&als[rbase + 16] = a1;
      *(f32x4_t*)&als[rbase + 32] = a2;
      *(f32x4_t*)&als[rbase + 48] = a3;
    }
    __syncthreads();

    if (tid < 256) {
      float rv = sigmoid_f(als[tid] + gr);
      float zv = sigmoid_f(als[256 + tid] + gz);
      float nv = tanh_f(gn + rv * (als[512 + tid] + bn));
      float hnew = (1.f - zv) * nv + zv * h;
      h = hnew;
      hsb[t * 256 + tid] = hnew;
      float other = __shfl_xor(hnew, 1);
      if ((tid & 1) == 0) hpk[(t + 1) & 1][tid >> 1] = packh2(hnew, other);
    }
    gr = grn;
    gz = gzn;
    gn = gnn;
    __syncthreads();  // hpk[t+1] ready for next step's MFMA phase
  }
}

// ---------------- banded softmax attention + ctx = h_global + attn ----------------
#define AW 80
__global__ void attn_kernel(const float* __restrict__ h_seq, const float* __restrict__ t,
                            float* __restrict__ ctx) {
  const int blk = blockIdx.x;
  const int b = blk >> 7;
  const int k0 = (blk & 127) << 4;  // 16 query rows per block
  const int tid = threadIdx.x;

  __shared__ __align__(16) float ewT[176][16];
  __shared__ float ts[176];
  __shared__ float tks[16];
  __shared__ float rden[16];

  const float* tb = t + b * 2048;
  if (tid < 176) {
    int j = k0 - AW + tid;
    ts[tid] = tb[min(max(j, 0), 2047)];
  }
  if (tid < 16) tks[tid] = tb[k0 + tid];
  __syncthreads();

  for (int p = tid; p < 176 * 16; p += 256) {
    int kk = p & 15, jr = p >> 4;
    int j = k0 - AW + jr;
    float d = 2048.f * (tks[kk] - ts[jr]);
    float e = (j >= 0 && j < 2048) ? __expf(-d * d) : 0.f;
    ewT[jr][kk] = e;
  }
  __syncthreads();

  if (tid < 16) {
    float s = 0.f;
    for (int jr = 0; jr < 176; jr++) s += ewT[jr][tid];
    rden[tid] = 1.f / s;
  }
  __syncthreads();

  float acc[16];
#pragma unroll
  for (int kk = 0; kk < 16; kk++) acc[kk] = 0.f;

  const float* hb = h_seq + b * 2048 * 256;
  for (int jr = 0; jr < 176; jr++) {
    int j = min(max(k0 - AW + jr, 0), 2047);
    float hv = hb[j * 256 + tid];
    const float4* e4 = (const float4*)ewT[jr];
    float4 e0 = e4[0], e1 = e4[1], e2 = e4[2], e3 = e4[3];
    acc[0] = fmaf(e0.x, hv, acc[0]);   acc[1] = fmaf(e0.y, hv, acc[1]);
    acc[2] = fmaf(e0.z, hv, acc[2]);   acc[3] = fmaf(e0.w, hv, acc[3]);
    acc[4] = fmaf(e1.x, hv, acc[4]);   acc[5] = fmaf(e1.y, hv, acc[5]);
    acc[6] = fmaf(e1.z, hv, acc[6]);   acc[7] = fmaf(e1.w, hv, acc[7]);
    acc[8] = fmaf(e2.x, hv, acc[8]);   acc[9] = fmaf(e2.y, hv, acc[9]);
    acc[10] = fmaf(e2.z, hv, acc[10]); acc[11] = fmaf(e2.w, hv, acc[11]);
    acc[12] = fmaf(e3.x, hv, acc[12]); acc[13] = fmaf(e3.y, hv, acc[13]);
    acc[14] = fmaf(e3.z, hv, acc[14]); acc[15] = fmaf(e3.w, hv, acc[15]);
  }

  float hg = hb[2047 * 256 + tid];
  float* cb = ctx + (b * 2048 + k0) * 256 + tid;
#pragma unroll
  for (int kk = 0; kk < 16; kk++) cb[kk * 256] = hg + acc[kk] * rden[kk];
}

// ---------------- init head: m0, s0, log_q0 ----------------
__global__ void init_head(const float* __restrict__ ctx, const float* __restrict__ WT1,
                          const float* __restrict__ bi1, const float* __restrict__ WT2,
                          const float* __restrict__ bi2, const float* __restrict__ eps0,
                          float* __restrict__ m0s0, float* __restrict__ lq0) {
  int b = blockIdx.x;
  int g = threadIdx.x;
  __shared__ float xs[256], his[256], ms[64], red[32];
  xs[g] = ctx[(b * 2048) * 256 + g];
  __syncthreads();
  float acc = bi1[g];
#pragma unroll 8
  for (int k = 0; k < 256; k++) acc = fmaf(WT1[k * 256 + g], xs[k], acc);
  his[g] = silu_f(acc);
  __syncthreads();
  if (g < 64) {
    float a2 = bi2[g];
#pragma unroll 8
    for (int k = 0; k < 256; k++) a2 = fmaf(WT2[k * 64 + g], his[k], a2);
    float v = (g < 32) ? a2 : (softplus_f(a2) + 1e-6f);
    m0s0[b * 64 + g] = v;
    ms[g] = v;
  }
  __syncthreads();
  if (g < 32) {
    float m = ms[g], s = ms[32 + g];
    float c0 = m + s * eps0[b * 32 + g];
    float sc = fmaxf(s, 1e-12f);
    float z = (c0 - m) / sc;
    red[g] = z * z + 2.f * __logf(sc) + LOG2PI_F;
  }
  __syncthreads();
  if (g == 0) {
    float s = 0.f;
    for (int i = 0; i < 32; i++) s += red[i];
    lq0[b] = -0.5f * s;
  }
}

// ---------------- step-head dense layer (M-tile=8) ----------------
__global__ void head_layer(const float* __restrict__ A, const float* __restrict__ WT,
                           const float* __restrict__ bias, const float* __restrict__ wext,
                           const float* __restrict__ tvec, float* __restrict__ C,
                           int N, int act) {
  int m0 = blockIdx.x * 8;
  int g = threadIdx.x;
  __shared__ __align__(16) float As[8][256];
#pragma unroll
  for (int r = 0; r < 8; r++) As[r][g] = A[(m0 + r) * 256 + g];
  __syncthreads();
  if (g < N) {
    float b0 = bias[g];
    float acc[8] = {b0, b0, b0, b0, b0, b0, b0, b0};
    for (int k4 = 0; k4 < 64; k4++) {
      const float* w = WT + (k4 * 4) * N + g;
      float w0v = w[0], w1v = w[N], w2v = w[2 * N], w3v = w[3 * N];
#pragma unroll
      for (int r = 0; r < 8; r++) {
        float4 xv = *(const float4*)(&As[r][k4 * 4]);
        acc[r] = fmaf(w0v, xv.x, acc[r]);
        acc[r] = fmaf(w1v, xv.y, acc[r]);
        acc[r] = fmaf(w2v, xv.z, acc[r]);
        acc[r] = fmaf(w3v, xv.w, acc[r]);
      }
    }
#pragma unroll
    for (int r = 0; r < 8; r++) {
      float a = acc[r];
      if (wext) a = fmaf(tvec[m0 + r], wext[g], a);
      if (act) a = silu_f(a);
      C[(m0 + r) * N + g] = a;
    }
  }
}

// ---------------- OU posterior: parallel segmented scan ----------------
__global__ __launch_bounds__(1024) void ou_kernel(
    const float* __restrict__ params, const float* __restrict__ t,
    const float* __restrict__ eps, const float* __restrict__ eps0,
    const float* __restrict__ m0s0, const float* __restrict__ lq0,
    float* __restrict__ out) {
  const int b = blockIdx.x;
  const int c = threadIdx.x & 31;
  const int s = threadIdx.x >> 5;  // segment 0..31
  const int k0 = s * 64;
  const int k1 = min(k0 + 64, 2047);
  const float* tb = t + b * 2048;

  __shared__ float Ps[32][33], Ss[32][33], Cs[32][33], lqs[32][33];

  float P = 1.f, S = 0.f, lq = 0.f;
  for (int k = k0; k < k1; k++) {
    const float* pr = params + (b * 2048 + k) * 96;
    float mu = pr[c];
    float kap = softplus_f(pr[32 + c]) + 1e-6f;
    float sg = softplus_f(pr[64 + c]) + 1e-6f;
    float dt = fmaxf(tb[k + 1] - tb[k], 1e-6f);
    float A = __expf(-kap * dt);
    float tkd = 2.f * kap * dt;
    float Qe = sg * sg * (1.f - A * A) / fmaxf(2.f * kap, 1e-12f);
    float kd = kap * dt;
    float Qt = sg * sg * dt * (1.f - kd + tkd * tkd * (1.f / 6.f));
    float var = fmaxf((tkd < 1e-6f) ? Qt : Qe, 1e-12f);
    float e = eps[(b * 2047 + k) * 32 + c];
    float d = mu * (1.f - A) + e * sqrtf(var);
    S = fmaf(A, S, d);
    P *= A;
    lq += e * e + __logf(var) + LOG2PI_F;
  }
  Ps[c][s] = P;
  Ss[c][s] = S;
  lqs[c][s] = lq;
  __syncthreads();

  if (s == 0) {
    float m0v = m0s0[b * 64 + c];
    float s0v = m0s0[b * 64 + 32 + c];
    float cc = fmaf(s0v, eps0[b * 32 + c], m0v);
    out[(b * 2048) * 32 + c] = cc;
    float lqt = 0.f;
    for (int i = 0; i < 32; i++) {
      Cs[c][i] = cc;
      cc = fmaf(Ps[c][i], cc, Ss[c][i]);
      lqt += lqs[c][i];
    }
    for (int off = 16; off >= 1; off >>= 1) lqt += __shfl_down(lqt, off, 32);
    if (c == 0) out[8 * 2048 * 32 + b] = lq0[b] - 0.5f * lqt;
  }
  __syncthreads();

  float cc = Cs[c][s];
  for (int k = k0; k < k1; k++) {
    const float* pr = params + (b * 2048 + k) * 96;
    float mu = pr[c];
    float kap = softplus_f(pr[32 + c]) + 1e-6f;
    float sg = softplus_f(pr[64 + c]) + 1e-6f;
    float dt = fmaxf(tb[k + 1] - tb[k], 1e-6f);
    float A = __expf(-kap * dt);
    float tkd = 2.f * kap * dt;
    float Qe = sg * sg * (1.f - A * A) / fmaxf(2.f * kap, 1e-12f);
    float kd = kap * dt;
    float Qt = sg * sg * dt * (1.f - kd + tkd * tkd * (1.f / 6.f));
    float var = fmaxf((tkd < 1e-6f) ? Qt : Qe, 1e-12f);
    float e = eps[(b * 2047 + k) * 32 + c];
    float d = mu * (1.f - A) + e * sqrtf(var);
    cc = fmaf(A, cc, d);
    out[(b * 2048 + k + 1) * 32 + c] = cc;
  }
}

// ---------------- launcher ----------------
extern "C" void kernel_launch(void* const* d_in, const int* in_sizes, int n_in,
                              void* d_out, int out_size, void* d_ws, size_t ws_size,
                              hipStream_t stream) {
  (void)in_sizes; (void)n_in; (void)out_size; (void)ws_size;
  const float* x    = (const float*)d_in[0];
  const float* t    = (const float*)d_in[1];
  const float* eps0 = (const float*)d_in[2];
  const float* eps  = (const float*)d_in[3];
  const float* W_ih = (const float*)d_in[4];
  const float* W_hh = (const float*)d_in[5];
  const float* b_ih = (const float*)d_in[6];
  const float* b_hh = (const float*)d_in[7];
  const float* Wi1  = (const float*)d_in[8];
  const float* bi1  = (const float*)d_in[9];
  const float* Wi2  = (const float*)d_in[10];
  const float* bi2  = (const float*)d_in[11];
  const float* Ws1  = (const float*)d_in[12];
  const float* bs1  = (const float*)d_in[13];
  const float* Ws2  = (const float*)d_in[14];
  const float* bs2  = (const float*)d_in[15];
  const float* Ws3  = (const float*)d_in[16];
  const float* bs3  = (const float*)d_in[17];
  float* out = (float*)d_out;
  float* ws = (float*)d_ws;

  // workspace layout (float offsets)
  float*        WT_ih = ws + 0;                        // 64x768   = 49152
  unsigned int* Wmf   = (unsigned int*)(ws + 49152);   // 98304 dwords (MFMA frags)
  float*        WT1   = ws + 147456;                   // 256x256  = 65536
  float*        WT2   = ws + 212992;                   // 256x64   = 16384
  float*        WTs1  = ws + 229376;                   // 257x256  = 65792
  float*        WTs2  = ws + 295168;                   // 256x256  = 65536
  float*        WTs3  = ws + 360704;                   // 256x96   = 24576
  float*        m0s0  = ws + 385280;                   // 8x64
  float*        lq0   = ws + 385792;                   // 8
  float*        gi    = ws + 385800;                   // 8x2048x768 = 12582912
  float*        h_seq = gi + 12582912;                 // 8x2048x256 = 4194304
  float*        ctx   = h_seq + 4194304;               // 8x2048x256 = 4194304
  // reuse gi region after GRU:
  float*        hs1    = gi;                           // 4194304
  float*        hs2    = gi + 4194304;                 // 4194304
  float*        params = gi + 8388608;                 // 8x2048x96 = 1572864

  // prep
  transpose_k<<<(768 * 64 + 255) / 256, 256, 0, stream>>>(W_ih, WT_ih, 768, 64);
  transpose_k<<<(256 * 256 + 255) / 256, 256, 0, stream>>>(Wi1, WT1, 256, 256);
  transpose_k<<<(64 * 256 + 255) / 256, 256, 0, stream>>>(Wi2, WT2, 64, 256);
  transpose_k<<<(256 * 257 + 255) / 256, 256, 0, stream>>>(Ws1, WTs1, 256, 257);
  transpose_k<<<(256 * 256 + 255) / 256, 256, 0, stream>>>(Ws2, WTs2, 256, 256);
  transpose_k<<<(96 * 256 + 255) / 256, 256, 0, stream>>>(Ws3, WTs3, 96, 256);
  whh_mfma_pack<<<384, 256, 0, stream>>>(W_hh, Wmf);

  // pipeline
  gi_gemm<<<2048, 256, 0, stream>>>(x, WT_ih, b_ih, b_hh, gi);
  gru_kernel<<<8, 768, 0, stream>>>((const uint4*)Wmf, gi, b_hh, h_seq);
  attn_kernel<<<1024, 256, 0, stream>>>(h_seq, t, ctx);
  init_head<<<8, 256, 0, stream>>>(ctx, WT1, bi1, WT2, bi2, eps0, m0s0, lq0);
  head_layer<<<2048, 256, 0, stream>>>(ctx, WTs1, bs1, WTs1 + 256 * 256, t, hs1, 256, 1);
  head_layer<<<2048, 256, 0, stream>>>(hs1, WTs2, bs2, nullptr, nullptr, hs2, 256, 1);
  head_layer<<<2048, 256, 0, stream>>>(hs2, WTs3, bs3, nullptr, nullptr, params, 96, 0);
  ou_kernel<<<8, 1024, 0, stream>>>(params, t, eps, eps0, m0s0, lq0, out);
}